// Round 1
// baseline (393.321 us; speedup 1.0000x reference)
//
#include <hip/hip_runtime.h>

typedef unsigned short u16;
typedef __attribute__((ext_vector_type(4))) unsigned short u16x4;
typedef __attribute__((ext_vector_type(8))) unsigned short u16x8;
typedef __attribute__((ext_vector_type(8))) short s16x8;
typedef __attribute__((ext_vector_type(4))) float f32x4;

__device__ __forceinline__ u16 f2bf(float f) {
  unsigned int u = __float_as_uint(f);
  u += 0x7FFFu + ((u >> 16) & 1u);   // RNE
  return (u16)(u >> 16);
}
__device__ __forceinline__ float bf2f(u16 h) {
  return __uint_as_float(((unsigned int)h) << 16);
}

// ---------------- fp32 -> bf16 convert (x4 vectorized) ----------------
__global__ __launch_bounds__(256) void cvt_kernel(const float* __restrict__ src,
                                                  u16* __restrict__ dst, int n4) {
  int i = blockIdx.x * 256 + threadIdx.x;
  if (i >= n4) return;
  float4 v = reinterpret_cast<const float4*>(src)[i];
  u16x4 o;
  o.x = f2bf(v.x); o.y = f2bf(v.y); o.z = f2bf(v.z); o.w = f2bf(v.w);
  reinterpret_cast<u16x4*>(dst)[i] = o;
}

// ---------------- GEMM: C[m][n] = sum_k A[m][k] * B[n][k] (B^T input) ----------------
// 128x128 tile, BK=32, 256 threads = 4 waves (2x2), each wave 64x64 via 4x4 mfma_16x16x32_bf16.
__device__ __forceinline__ void store_out(float* p, float v) { *p = v; }
__device__ __forceinline__ void store_out(u16* p, float v) { *p = f2bf(v); }

template <typename OutT>
__global__ __launch_bounds__(256) void gemm_bt(const u16* __restrict__ A,
                                               const u16* __restrict__ Bw,
                                               OutT* __restrict__ C, int N, int K) {
  __shared__ u16 As[128 * 32];
  __shared__ u16 Bs[128 * 32];
  const int tid = threadIdx.x;
  const int lane = tid & 63;
  const int wave = tid >> 6;
  const int wm = wave >> 1, wn = wave & 1;
  const int lh = lane & 15, quad = lane >> 4;
  const int m0 = blockIdx.y * 128, n0 = blockIdx.x * 128;

  f32x4 acc[4][4];
#pragma unroll
  for (int i = 0; i < 4; ++i)
#pragma unroll
    for (int j = 0; j < 4; ++j) { acc[i][j][0] = 0.f; acc[i][j][1] = 0.f; acc[i][j][2] = 0.f; acc[i][j][3] = 0.f; }

  const int c0 = tid, c1 = tid + 256;
  const int r0 = c0 >> 2, k0c = (c0 & 3) * 8;
  const int r1 = c1 >> 2, k1c = (c1 & 3) * 8;
  const int nkt = K >> 5;
  for (int kt = 0; kt < nkt; ++kt) {
    const int kb = kt * 32;
    u16x8 av0 = *reinterpret_cast<const u16x8*>(A + (size_t)(m0 + r0) * K + kb + k0c);
    u16x8 av1 = *reinterpret_cast<const u16x8*>(A + (size_t)(m0 + r1) * K + kb + k1c);
    u16x8 bv0 = *reinterpret_cast<const u16x8*>(Bw + (size_t)(n0 + r0) * K + kb + k0c);
    u16x8 bv1 = *reinterpret_cast<const u16x8*>(Bw + (size_t)(n0 + r1) * K + kb + k1c);
    __syncthreads();  // prior tile's LDS reads done
    reinterpret_cast<u16x8*>(As)[c0] = av0;
    reinterpret_cast<u16x8*>(As)[c1] = av1;
    reinterpret_cast<u16x8*>(Bs)[c0] = bv0;
    reinterpret_cast<u16x8*>(Bs)[c1] = bv1;
    __syncthreads();  // staged tile visible
    s16x8 af[4], bf4[4];
#pragma unroll
    for (int mb = 0; mb < 4; ++mb)
      af[mb] = *reinterpret_cast<const s16x8*>(&As[(wm * 64 + mb * 16 + lh) * 32 + quad * 8]);
#pragma unroll
    for (int nb = 0; nb < 4; ++nb)
      bf4[nb] = *reinterpret_cast<const s16x8*>(&Bs[(wn * 64 + nb * 16 + lh) * 32 + quad * 8]);
#pragma unroll
    for (int mb = 0; mb < 4; ++mb)
#pragma unroll
      for (int nb = 0; nb < 4; ++nb)
        acc[mb][nb] = __builtin_amdgcn_mfma_f32_16x16x32_bf16(af[mb], bf4[nb], acc[mb][nb], 0, 0, 0);
  }
#pragma unroll
  for (int mb = 0; mb < 4; ++mb)
#pragma unroll
    for (int nb = 0; nb < 4; ++nb) {
      const int col = n0 + wn * 64 + nb * 16 + lh;
#pragma unroll
      for (int r = 0; r < 4; ++r) {
        const int row = m0 + wm * 64 + mb * 16 + quad * 4 + r;
        store_out(&C[(size_t)row * N + col], acc[mb][nb][r]);
      }
    }
}

// ---------------- RoPE: raw QKV (4096 x 3072 bf16) -> Q,K in (B,H,S,64) bf16 ----------------
__global__ __launch_bounds__(256) void rope_kernel(const u16* __restrict__ raw,
                                                   u16* __restrict__ Qo, u16* __restrict__ Ko) {
  int idx = blockIdx.x * 256 + threadIdx.x;  // 0 .. 4194303
  int which = idx >> 21;                     // 0 = Q, 1 = K
  int id = idx & 0x1FFFFF;
  int d = id & 31;
  int s = (id >> 5) & 2047;
  int bh = id >> 16;                         // b*16 + h
  int b = bh >> 4;
  int h = bh & 15;
  const u16* r = raw + (size_t)(b * 2048 + s) * 3072 + which * 1024 + h * 64 + d;
  float v1 = bf2f(r[0]);
  float v2 = bf2f(r[32]);
  float invf = __expf((float)d * -0.2878231366f);  // 10000^(-d/32)
  float ang = (float)s * invf;
  float sv, cv;
  __sincosf(ang, &sv, &cv);
  u16* o = (which ? Ko : Qo) + (size_t)(bh * 2048 + s) * 64 + d;
  o[0]  = f2bf(v1 * cv - v2 * sv);
  o[32] = f2bf(v2 * cv + v1 * sv);
}

// ---------------- V transpose: raw V cols -> Vt (B,H,64,S) bf16 ----------------
__global__ __launch_bounds__(256) void transpose_v(const u16* __restrict__ raw,
                                                   u16* __restrict__ Vt) {
  int st = blockIdx.x, bh = blockIdx.y;
  int b = bh >> 4, h = bh & 15;
  __shared__ u16 tile[64 * 72];
  int tid = threadIdx.x;
#pragma unroll
  for (int it = 0; it < 4; ++it) {
    int c = it * 256 + tid;          // 0..1023 ushort4 chunks
    int sr = c >> 4, d4 = c & 15;
    u16x4 v = *reinterpret_cast<const u16x4*>(
        raw + (size_t)(b * 2048 + st * 64 + sr) * 3072 + 2048 + h * 64 + d4 * 4);
    *reinterpret_cast<u16x4*>(&tile[sr * 72 + d4 * 4]) = v;
  }
  __syncthreads();
#pragma unroll
  for (int it = 0; it < 4; ++it) {
    int c = it * 256 + tid;
    int dd = c >> 4, s4 = c & 15;
    u16x4 v;
#pragma unroll
    for (int j = 0; j < 4; ++j) v[j] = tile[(s4 * 4 + j) * 72 + dd];
    *reinterpret_cast<u16x4*>(Vt + (size_t)(bh * 64 + dd) * 2048 + st * 64 + s4 * 4) = v;
  }
}

// ---------------- flash-style causal amplified attention ----------------
// grid: (S/64, B*H); 256 thr = 4 waves, each wave owns 16 Q rows.
// score = (q.k + 0.1*(q^2).(k^2)) / 8, scale folded into q-fragments.
__global__ __launch_bounds__(256) void attn_kernel(const u16* __restrict__ Qr,
                                                   const u16* __restrict__ Kr,
                                                   const u16* __restrict__ Vt,
                                                   const float* __restrict__ gate,
                                                   u16* __restrict__ attn) {
  const int qt = blockIdx.x, bh = blockIdx.y;
  const int tid = threadIdx.x, lane = tid & 63, wave = tid >> 6;
  const int lh = lane & 15, quad = lane >> 4;
  const int b = bh >> 4, h = bh & 15;
  __shared__ u16 Pbuf[4][16 * 72];
  u16* myP = &Pbuf[wave][0];
  const int qrow0 = qt * 64 + wave * 16;

  // Q fragments (A-layout): m = lh, k = kk*32 + quad*8 + j
  s16x8 qs[2], q2s[2];
  {
    const u16* qbase = Qr + (size_t)(bh * 2048 + qrow0 + lh) * 64 + quad * 8;
#pragma unroll
    for (int kk = 0; kk < 2; ++kk) {
      u16x8 qv = *reinterpret_cast<const u16x8*>(qbase + kk * 32);
#pragma unroll
      for (int j = 0; j < 8; ++j) {
        float f = bf2f(qv[j]);
        qs[kk][j]  = (short)f2bf(f * 0.125f);     // 1/sqrt(64)
        q2s[kk][j] = (short)f2bf(f * f * 0.0125f); // lambda/sqrt(64)
      }
    }
  }

  float m_st[4], l_st[4];
  f32x4 oacc[4];
#pragma unroll
  for (int r = 0; r < 4; ++r) { m_st[r] = -1e30f; l_st[r] = 0.f; }
#pragma unroll
  for (int nb = 0; nb < 4; ++nb) { oacc[nb][0] = 0.f; oacc[nb][1] = 0.f; oacc[nb][2] = 0.f; oacc[nb][3] = 0.f; }
  float gw[4];
#pragma unroll
  for (int nb = 0; nb < 4; ++nb) gw[nb] = gate[nb * 16 + lh];

  for (int kt = 0; kt <= qt; ++kt) {
    f32x4 sacc[4];
#pragma unroll
    for (int nb = 0; nb < 4; ++nb) { sacc[nb][0] = 0.f; sacc[nb][1] = 0.f; sacc[nb][2] = 0.f; sacc[nb][3] = 0.f; }
#pragma unroll
    for (int kk = 0; kk < 2; ++kk) {
#pragma unroll
      for (int nb = 0; nb < 4; ++nb) {
        const u16* kp = Kr + (size_t)(bh * 2048 + kt * 64 + nb * 16 + lh) * 64 + kk * 32 + quad * 8;
        u16x8 kv = *reinterpret_cast<const u16x8*>(kp);
        s16x8 kf, k2f;
#pragma unroll
        for (int j = 0; j < 8; ++j) {
          float f = bf2f(kv[j]);
          kf[j]  = (short)kv[j];
          k2f[j] = (short)f2bf(f * f);
        }
        sacc[nb] = __builtin_amdgcn_mfma_f32_16x16x32_bf16(qs[kk], kf, sacc[nb], 0, 0, 0);
        sacc[nb] = __builtin_amdgcn_mfma_f32_16x16x32_bf16(q2s[kk], k2f, sacc[nb], 0, 0, 0);
      }
    }
    if (kt == qt) {  // causal mask on the diagonal tile
#pragma unroll
      for (int nb = 0; nb < 4; ++nb) {
        const int colg = kt * 64 + nb * 16 + lh;
#pragma unroll
        for (int r = 0; r < 4; ++r) {
          const int rowg = qrow0 + quad * 4 + r;
          if (colg > rowg) sacc[nb][r] = -1e9f;
        }
      }
    }
    // online softmax (state per row; 16 lanes of a quad share 4 rows)
    float mnew[4];
#pragma unroll
    for (int r = 0; r < 4; ++r) {
      float mx = fmaxf(fmaxf(sacc[0][r], sacc[1][r]), fmaxf(sacc[2][r], sacc[3][r]));
#pragma unroll
      for (int off = 1; off < 16; off <<= 1) mx = fmaxf(mx, __shfl_xor(mx, off));
      mnew[r] = fmaxf(m_st[r], mx);
    }
    float p[4][4];
#pragma unroll
    for (int nb = 0; nb < 4; ++nb)
#pragma unroll
      for (int r = 0; r < 4; ++r) p[nb][r] = __expf(sacc[nb][r] - mnew[r]);
#pragma unroll
    for (int r = 0; r < 4; ++r) {
      float rs = p[0][r] + p[1][r] + p[2][r] + p[3][r];
#pragma unroll
      for (int off = 1; off < 16; off <<= 1) rs += __shfl_xor(rs, off);
      float alpha = __expf(m_st[r] - mnew[r]);
      l_st[r] = l_st[r] * alpha + rs;
      m_st[r] = mnew[r];
#pragma unroll
      for (int nb = 0; nb < 4; ++nb) oacc[nb][r] *= alpha;
    }
    // P: C-layout -> LDS -> A-layout (wave-private, no barrier needed)
#pragma unroll
    for (int nb = 0; nb < 4; ++nb)
#pragma unroll
      for (int r = 0; r < 4; ++r)
        myP[(quad * 4 + r) * 72 + nb * 16 + lh] = f2bf(p[nb][r]);
#pragma unroll
    for (int kk = 0; kk < 2; ++kk) {
      s16x8 pf = *reinterpret_cast<const s16x8*>(&myP[lh * 72 + kk * 32 + quad * 8]);
#pragma unroll
      for (int nb = 0; nb < 4; ++nb) {
        const u16* vp = Vt + (size_t)(bh * 64 + nb * 16 + lh) * 2048 + kt * 64 + kk * 32 + quad * 8;
        u16x8 vv = *reinterpret_cast<const u16x8*>(vp);
        s16x8 vf;
#pragma unroll
        for (int j = 0; j < 8; ++j) vf[j] = (short)vv[j];
        oacc[nb] = __builtin_amdgcn_mfma_f32_16x16x32_bf16(pf, vf, oacc[nb], 0, 0, 0);
      }
    }
  }
  // finalize: o/l, epilogue o + 0.05*o^2*g[d] (out2==out1 identity)
  float invl[4];
#pragma unroll
  for (int r = 0; r < 4; ++r) invl[r] = 1.0f / l_st[r];
#pragma unroll
  for (int nb = 0; nb < 4; ++nb)
#pragma unroll
    for (int r = 0; r < 4; ++r) {
      float o = oacc[nb][r] * invl[r];
      float val = o + 0.05f * o * o * gw[nb];
      const int rows = qrow0 + quad * 4 + r;
      attn[(size_t)(b * 2048 + rows) * 1024 + h * 64 + nb * 16 + lh] = f2bf(val);
    }
}

extern "C" void kernel_launch(void* const* d_in, const int* in_sizes, int n_in,
                              void* d_out, int out_size, void* d_ws, size_t ws_size,
                              hipStream_t stream) {
  (void)in_sizes; (void)n_in; (void)out_size; (void)ws_size;
  const float* x    = (const float*)d_in[0];
  const float* Wq   = (const float*)d_in[1];
  const float* Wk   = (const float*)d_in[2];
  const float* Wv   = (const float*)d_in[3];
  const float* Wo   = (const float*)d_in[4];
  const float* gate = (const float*)d_in[5];

  u16* ws    = (u16*)d_ws;
  u16* xbf   = ws;                    // 4096x1024
  u16* wbf   = xbf + 4194304;         // 3072x1024 (Wq|Wk|Wv rows)
  u16* wobf  = wbf + 3145728;         // 1024x1024
  u16* raw   = wobf + 1048576;        // 4096x3072 QKV gemm out
  u16* Qb    = raw + 12582912;        // (B,H,S,64)
  u16* Kb    = Qb + 4194304;          // (B,H,S,64)
  u16* Vtb   = Kb + 4194304;          // (B,H,64,S)
  u16* attnb = Vtb + 4194304;         // 4096x1024

  cvt_kernel<<<4096, 256, 0, stream>>>(x, xbf, 1048576);
  cvt_kernel<<<1024, 256, 0, stream>>>(Wq, wbf, 262144);
  cvt_kernel<<<1024, 256, 0, stream>>>(Wk, wbf + 1048576, 262144);
  cvt_kernel<<<1024, 256, 0, stream>>>(Wv, wbf + 2097152, 262144);
  cvt_kernel<<<1024, 256, 0, stream>>>(Wo, wobf, 262144);

  gemm_bt<u16><<<dim3(24, 32), 256, 0, stream>>>(xbf, wbf, raw, 3072, 1024);
  rope_kernel<<<16384, 256, 0, stream>>>(raw, Qb, Kb);
  transpose_v<<<dim3(32, 32), 256, 0, stream>>>(raw, Vtb);
  attn_kernel<<<dim3(32, 32), 256, 0, stream>>>(Qb, Kb, Vtb, gate, attnb);
  gemm_bt<float><<<dim3(8, 32), 256, 0, stream>>>(attnb, wobf, (float*)d_out, 1024, 1024);
}